// Round 4
// baseline (361.984 us; speedup 1.0000x reference)
//
#include <hip/hip_runtime.h>
#include <math.h>

#define BATCH 8
#define CCH 384
#define NPIX 4096
#define NHEADS 6
#define SZ ((size_t)BATCH * CCH * NPIX) // elements per (B,C,N) buffer

typedef __attribute__((ext_vector_type(8))) short short8;  // 8 bf16 = 4 VGPR
typedef __attribute__((ext_vector_type(4))) float f32x4;   // MFMA acc

__device__ __forceinline__ float elu1(float x) { return x > 0.f ? x + 1.f : expf(x); }

__device__ __forceinline__ unsigned short bf16_rne(float f) {
    unsigned u = __builtin_bit_cast(unsigned, f);
    u += 0x7FFFu + ((u >> 16) & 1u);
    return (unsigned short)(u >> 16);
}
__device__ __forceinline__ float bf16_f(unsigned short h) {
    return __builtin_bit_cast(float, ((unsigned)h) << 16);
}
__device__ __forceinline__ unsigned packsplit(float v) {
    unsigned short hi = bf16_rne(v);
    unsigned short lo = bf16_rne(v - bf16_f(hi));
    return ((unsigned)hi << 16) | (unsigned)lo;
}

// LDS XOR swizzle for the GEMM B-tile, in u32 index units.
// idx = k*128 + col; swizzle XORs bits 2..4 with k's low bits.
// Writes (uint4, 4 lanes..): uniform bank-groups; reads (b32 col-strided):
// 2 lanes/bank (g, g+2 alias) = free.
__device__ __forceinline__ int bswz(int idx, int k) {
    return idx ^ ((k & 7) << 2) ^ (((k >> 3) & 1) << 4);
}

// ---------------------------------------------------------------------------
// Trig table: T[f][pos] = (sin, cos) of pos * 10000^(-f/96), f in 0..95, pos 0..63
// ---------------------------------------------------------------------------
__global__ __launch_bounds__(256) void trig_kernel(float2* __restrict__ T)
{
    const float KC = 0.13841367062030680f; // log2(10000)/96
    int idx = blockIdx.x * 256 + threadIdx.x; // 0..6143
    int f = idx >> 6, pos = idx & 63;
    float ang = (float)pos * exp2f(-KC * (float)f);
    float s, c;
    sincosf(ang, &s, &c);
    T[idx] = make_float2(s, c);
}

// ---------------------------------------------------------------------------
// Pack W (q,k,v,fc) into MFMA A-fragment order, split hi/lo bf16.
// f-blocks: 0..23 q (rope-permuted rows), 24..47 k, 48..71 v, 72..95 fc.
// Wp[f*12288 + c*1024 + hilo*512 + lane*8 + j] = W[ch(f,lane&15)][c*32+(lane>>4)*8+j]
// ---------------------------------------------------------------------------
__global__ __launch_bounds__(256) void pack_w_kernel(
    const float* __restrict__ Wq, const float* __restrict__ Wk,
    const float* __restrict__ Wv, const float* __restrict__ Wfc,
    unsigned short* __restrict__ Wp)
{
    const int tid = threadIdx.x;
    const int lane = tid & 63;
    const int f = blockIdx.x * 4 + (tid >> 6); // 0..95
    const int rloc = lane & 15;
    const int ks = (lane >> 4) * 8;

    const float* Wsel;
    int ch;
    if (f < 72) {
        int which = f / 24;
        int r = (f % 24) * 16 + rloc;
        if (which < 2) {
            int u = r >> 1;
            int cu = (u < 96) ? u : u + 96;
            ch = cu + 96 * (r & 1);
        } else {
            ch = r;
        }
        Wsel = (which == 0) ? Wq : (which == 1) ? Wk : Wv;
    } else {
        ch = (f - 72) * 16 + rloc;
        Wsel = Wfc;
    }

    for (int c = 0; c < 12; ++c) {
        short8 hv, lv;
#pragma unroll
        for (int j = 0; j < 8; ++j) {
            float v = Wsel[(size_t)ch * CCH + c * 32 + ks + j];
            unsigned short h = bf16_rne(v);
            hv[j] = (short)h;
            lv[j] = (short)bf16_rne(v - bf16_f(h));
        }
        size_t off = (size_t)f * 12288 + (size_t)c * 1024 + (size_t)lane * 8;
        *(short8*)(Wp + off) = hv;
        *(short8*)(Wp + off + 512) = lv;
    }
}

// ---------------------------------------------------------------------------
// Split-bf16 MFMA GEMM.
// MODE 0: Xin = fp32 x (B,C,N); staging converts fp32 -> packed u32 in LDS.
//         M=1152 (q,k,v stacked, q/k rows permuted), rope(table)+elu epilogue.
// MODE 1: Xin = u32-packed (hi<<16|lo) attn output; staging = pure copy.
//         M=384 (fc), bias epilogue, fp32 out.
// Block 256 thr = 4 waves (2m x 2n of 64x64), tile 128x128, BK=32.
// LDS: linear [32][128] u32 with XOR swizzle (bswz) - conflict-free both sides.
// acc[i][jj][reg]: m = mt*64+i*16+(lane>>4)*4+reg, n = nblk*128+wn*64+jj*16+(lane&15)
// ---------------------------------------------------------------------------
template <int MODE>
__global__ __launch_bounds__(256, 2) void mfma_gemm(
    const void* __restrict__ Xin,
    const unsigned short* __restrict__ Wp,
    const float2* __restrict__ Ttab,
    const float* __restrict__ b0, const float* __restrict__ b1, const float* __restrict__ b2,
    float* __restrict__ O0, float* __restrict__ O1, float* __restrict__ O2)
{
    __shared__ unsigned Bs[32 * 128];

    const int tid = threadIdx.x;
    const int lane = tid & 63;
    const int wave = tid >> 6;
    const int wm = wave >> 1, wn = wave & 1;
    const int mt = blockIdx.y * 2 + wm;       // 64-row tile idx
    const int nblk = blockIdx.x;
    const int b = blockIdx.z;
    const int g = lane >> 4;                  // 0..3
    const int ln = lane & 15;

    f32x4 acc[4][4] = {};

    const int sr = tid >> 3;                  // staging row (k) 0..31
    const int sc = (tid & 7) * 16;            // staging col base
    const int swx = ((sr & 7) << 2) | (((sr >> 3) & 1) << 4); // write XOR mask
    const unsigned short* wbase = Wp + (size_t)(mt * 4) * 12288 + (size_t)lane * 8;

    const float* sbF = (const float*)Xin + (size_t)b * CCH * NPIX + nblk * 128 + sc;
    const unsigned* sbU = (const unsigned*)Xin + (size_t)b * CCH * NPIX + nblk * 128 + sc;

#pragma unroll 1
    for (int c = 0; c < 12; ++c) {
        __syncthreads();
        if (MODE == 0) {
            const float* src = sbF + (size_t)(c * 32 + sr) * NPIX;
            float vals[16];
            *(float4*)&vals[0]  = *(const float4*)(src + 0);
            *(float4*)&vals[4]  = *(const float4*)(src + 4);
            *(float4*)&vals[8]  = *(const float4*)(src + 8);
            *(float4*)&vals[12] = *(const float4*)(src + 12);
            const int rb = sr * 128 + sc;
#pragma unroll
            for (int w = 0; w < 4; ++w) {
                uint4 o;
                o.x = packsplit(vals[w * 4 + 0]);
                o.y = packsplit(vals[w * 4 + 1]);
                o.z = packsplit(vals[w * 4 + 2]);
                o.w = packsplit(vals[w * 4 + 3]);
                *(uint4*)&Bs[(rb + 4 * w) ^ swx] = o;
            }
        } else {
            const unsigned* src = sbU + (size_t)(c * 32 + sr) * NPIX;
            uint4 v0 = *(const uint4*)(src + 0);
            uint4 v1 = *(const uint4*)(src + 4);
            uint4 v2 = *(const uint4*)(src + 8);
            uint4 v3 = *(const uint4*)(src + 12);
            const int rb = sr * 128 + sc;
            *(uint4*)&Bs[(rb + 0)  ^ swx] = v0;
            *(uint4*)&Bs[(rb + 4)  ^ swx] = v1;
            *(uint4*)&Bs[(rb + 8)  ^ swx] = v2;
            *(uint4*)&Bs[(rb + 12) ^ swx] = v3;
        }
        __syncthreads();

        short8 ah[4], al[4];
#pragma unroll
        for (int i = 0; i < 4; ++i) {
            const unsigned short* p = wbase + (size_t)i * 12288 + c * 1024;
            ah[i] = *(const short8*)(p);
            al[i] = *(const short8*)(p + 512);
        }

#pragma unroll
        for (int jj = 0; jj < 4; ++jj) {
            const int col = wn * 64 + jj * 16 + ln;
            short8 bh, bl;
#pragma unroll
            for (int j = 0; j < 8; ++j) {
                const int k = g * 8 + j;
                unsigned uu = Bs[(k * 128 + col) ^ ((j & 7) << 2) ^ (((g & 1)) << 4)];
                bh[j] = (short)(uu >> 16);
                bl[j] = (short)(uu & 0xFFFFu);
            }
#pragma unroll
            for (int i = 0; i < 4; ++i) {
                acc[i][jj] = __builtin_amdgcn_mfma_f32_16x16x32_bf16(ah[i], bh, acc[i][jj], 0, 0, 0);
                acc[i][jj] = __builtin_amdgcn_mfma_f32_16x16x32_bf16(ah[i], bl, acc[i][jj], 0, 0, 0);
                acc[i][jj] = __builtin_amdgcn_mfma_f32_16x16x32_bf16(al[i], bh, acc[i][jj], 0, 0, 0);
            }
        }
    }

    const int ncol0 = nblk * 128 + wn * 64 + ln;

    if (MODE == 1) {
#pragma unroll
        for (int i = 0; i < 4; ++i) {
            const int rowb = mt * 64 + i * 16 + g * 4;
#pragma unroll
            for (int r = 0; r < 4; ++r) {
                const int row = rowb + r;
                const float bias = b0[row];
                float* orow = O0 + ((size_t)b * CCH + row) * NPIX;
#pragma unroll
                for (int jj = 0; jj < 4; ++jj)
                    orow[ncol0 + jj * 16] = acc[i][jj][r] + bias;
            }
        }
    } else {
        const int which = mt / 6;
        const int mloc = (mt % 6) * 64;
        const float* bsel = (which == 0) ? b0 : (which == 1) ? b1 : b2;
        float* osel = (which == 0) ? O0 : (which == 1) ? O1 : O2;
        if (which == 2) {
            // v: plain bias, fp32 out
#pragma unroll
            for (int i = 0; i < 4; ++i) {
                const int rowb = mloc + i * 16 + g * 4;
#pragma unroll
                for (int r = 0; r < 4; ++r) {
                    const int row = rowb + r;
                    const float bias = bsel[row];
                    float* orow = osel + ((size_t)b * CCH + row) * NPIX;
#pragma unroll
                    for (int jj = 0; jj < 4; ++jj)
                        orow[ncol0 + jj * 16] = acc[i][jj][r] + bias;
                }
            }
        } else {
            const float qs = (which == 0) ? 0.125f : 1.0f; // hd^-0.5 pre-elu for q
            const int posH = nblk * 2 + wn;                // n>>6, thread-constant
#pragma unroll
            for (int i = 0; i < 4; ++i) {
#pragma unroll
                for (int p = 0; p < 2; ++p) {
                    const int re = mloc + i * 16 + g * 4 + 2 * p; // even permuted row
                    const int u = re >> 1;
                    const bool isH = (u < 96);
                    const int cu = isH ? u : u + 96;
                    const int jA = isH ? (u >> 1) : ((u - 96) >> 1);
                    const float be = bsel[cu];
                    const float bo = bsel[cu + 96];
                    float* orE = osel + ((size_t)b * CCH + cu) * NPIX;
                    float* orO = orE + (size_t)96 * NPIX;
                    const float2* Ta = Ttab + jA * 64;
                    const float2* Tb = Ttab + (jA + 48) * 64;
                    if (isH) {
                        const float2 fa = Ta[posH];
                        const float2 fb = Tb[posH];
#pragma unroll
                        for (int jj = 0; jj < 4; ++jj) {
                            const int n = ncol0 + jj * 16;
                            const float te = acc[i][jj][2 * p] + be;
                            const float to = acc[i][jj][2 * p + 1] + bo;
                            orE[n] = elu1((te * fa.y - to * fa.x) * qs);
                            orO[n] = elu1((to * fb.y + te * fb.x) * qs);
                        }
                    } else {
#pragma unroll
                        for (int jj = 0; jj < 4; ++jj) {
                            const int n = ncol0 + jj * 16;
                            const int pw = jj * 16 + ln; // n & 63
                            const float2 fa = Ta[pw];
                            const float2 fb = Tb[pw];
                            const float te = acc[i][jj][2 * p] + be;
                            const float to = acc[i][jj][2 * p + 1] + bo;
                            orE[n] = elu1((te * fa.y - to * fa.x) * qs);
                            orO[n] = elu1((to * fb.y + te * fb.x) * qs);
                        }
                    }
                }
            }
        }
    }
}

// ---------------------------------------------------------------------------
// kv[bh][d][e] = sum_n k[b,64h+d,n] * v[b,64h+e,n];  ksum[bh][d] = sum_n k
// ---------------------------------------------------------------------------
__global__ __launch_bounds__(256) void kv_kernel(
    const float* __restrict__ Kin, const float* __restrict__ Vin,
    float* __restrict__ KV, float* __restrict__ KS)
{
    __shared__ float Ks[32][68];
    __shared__ float Vs[32][68];
    const int tid = threadIdx.x;
    const int bh = blockIdx.x;
    const int ns = blockIdx.y;
    const int b = bh / NHEADS, h = bh % NHEADS;
    const float* kb = Kin + ((size_t)b * CCH + h * 64) * NPIX;
    const float* vb = Vin + ((size_t)b * CCH + h * 64) * NPIX;
    const int drow = tid >> 2;
    const int nl = (tid & 3) * 8;
    const int td = (tid & 15) * 4;
    const int te = (tid >> 4) * 4;

    float acc[4][4];
    float ks[4] = {0.f, 0.f, 0.f, 0.f};
#pragma unroll
    for (int i = 0; i < 4; ++i)
#pragma unroll
        for (int j = 0; j < 4; ++j) acc[i][j] = 0.f;

    for (int n0 = ns * 256; n0 < ns * 256 + 256; n0 += 32) {
        __syncthreads();
        const float* kr = kb + (size_t)drow * NPIX + n0 + nl;
        const float* vr = vb + (size_t)drow * NPIX + n0 + nl;
        float4 k0 = *(const float4*)kr;
        float4 k1 = *(const float4*)(kr + 4);
        float4 v0 = *(const float4*)vr;
        float4 v1 = *(const float4*)(vr + 4);
        Ks[nl + 0][drow] = k0.x; Ks[nl + 1][drow] = k0.y;
        Ks[nl + 2][drow] = k0.z; Ks[nl + 3][drow] = k0.w;
        Ks[nl + 4][drow] = k1.x; Ks[nl + 5][drow] = k1.y;
        Ks[nl + 6][drow] = k1.z; Ks[nl + 7][drow] = k1.w;
        Vs[nl + 0][drow] = v0.x; Vs[nl + 1][drow] = v0.y;
        Vs[nl + 2][drow] = v0.z; Vs[nl + 3][drow] = v0.w;
        Vs[nl + 4][drow] = v1.x; Vs[nl + 5][drow] = v1.y;
        Vs[nl + 6][drow] = v1.z; Vs[nl + 7][drow] = v1.w;
        __syncthreads();
#pragma unroll 8
        for (int nn = 0; nn < 32; ++nn) {
            float4 a = *(const float4*)&Ks[nn][td];
            float4 w = *(const float4*)&Vs[nn][te];
            float av[4] = {a.x, a.y, a.z, a.w};
            float wv[4] = {w.x, w.y, w.z, w.w};
            ks[0] += av[0]; ks[1] += av[1]; ks[2] += av[2]; ks[3] += av[3];
#pragma unroll
            for (int i = 0; i < 4; ++i)
#pragma unroll
                for (int j = 0; j < 4; ++j) acc[i][j] += av[i] * wv[j];
        }
    }

    float* kvb = KV + (size_t)bh * 64 * 64;
#pragma unroll
    for (int i = 0; i < 4; ++i)
#pragma unroll
        for (int j = 0; j < 4; ++j)
            atomicAdd(&kvb[(td + i) * 64 + (te + j)], acc[i][j]);
    if (te == 0) {
#pragma unroll
        for (int i = 0; i < 4; ++i) atomicAdd(&KS[bh * 64 + td + i], ks[i]);
    }
}

// ---------------------------------------------------------------------------
// out[b,64h+e,n] = (sum_d q*kv) / (sum_d q*ksum + 1e-6), written PACKED u32.
// ---------------------------------------------------------------------------
__global__ __launch_bounds__(256) void attn_kernel(
    const float* __restrict__ Q, const float* __restrict__ KV,
    const float* __restrict__ KS, unsigned* __restrict__ O)
{
    __shared__ float Qs[64][132];
    __shared__ float KVs[64][64];
    __shared__ float KSs[64];
    const int tid = threadIdx.x;
    const int n0 = blockIdx.x * 128;
    const int bh = blockIdx.y;
    const int b = bh / NHEADS, h = bh % NHEADS;
    const float* qb = Q + ((size_t)b * CCH + h * 64) * NPIX;

    {
        const int row = tid >> 2;
        const int c0 = (tid & 3) * 32;
        const float* qr = qb + (size_t)row * NPIX + n0 + c0;
#pragma unroll
        for (int j = 0; j < 8; ++j)
            *(float4*)&Qs[row][c0 + j * 4] = *(const float4*)&qr[j * 4];
        const int kc = (tid & 3) * 16;
        const float* kvr = KV + (size_t)bh * 4096 + (size_t)row * 64 + kc;
#pragma unroll
        for (int j = 0; j < 4; ++j)
            *(float4*)&KVs[row][kc + j * 4] = *(const float4*)&kvr[j * 4];
        if (tid < 64) KSs[tid] = KS[bh * 64 + tid];
    }
    __syncthreads();

    const int tx = tid & 31;
    const int ty = tid >> 5;
    float acc[8][4];
    float accn[4] = {0.f, 0.f, 0.f, 0.f};
#pragma unroll
    for (int r = 0; r < 8; ++r)
#pragma unroll
        for (int j = 0; j < 4; ++j) acc[r][j] = 0.f;

#pragma unroll 8
    for (int d = 0; d < 64; ++d) {
        float4 qv = *(const float4*)&Qs[d][tx * 4];
        float qa[4] = {qv.x, qv.y, qv.z, qv.w};
        float ksv = KSs[d];
#pragma unroll
        for (int j = 0; j < 4; ++j) accn[j] += ksv * qa[j];
        float4 k0 = *(const float4*)&KVs[d][ty * 8];
        float4 k1 = *(const float4*)&KVs[d][ty * 8 + 4];
        float kva[8] = {k0.x, k0.y, k0.z, k0.w, k1.x, k1.y, k1.z, k1.w};
#pragma unroll
        for (int r = 0; r < 8; ++r)
#pragma unroll
            for (int j = 0; j < 4; ++j) acc[r][j] += kva[r] * qa[j];
    }

    float rcp[4];
#pragma unroll
    for (int j = 0; j < 4; ++j) rcp[j] = 1.f / (accn[j] + 1e-6f);
#pragma unroll
    for (int r = 0; r < 8; ++r) {
        unsigned* orow = O + ((size_t)b * CCH + h * 64 + ty * 8 + r) * NPIX + n0 + tx * 4;
        uint4 o4;
        o4.x = packsplit(acc[r][0] * rcp[0]);
        o4.y = packsplit(acc[r][1] * rcp[1]);
        o4.z = packsplit(acc[r][2] * rcp[2]);
        o4.w = packsplit(acc[r][3] * rcp[3]);
        *(uint4*)orow = o4;
    }
}

__global__ void zero_kernel(float* p, int n)
{
    int i = blockIdx.x * blockDim.x + threadIdx.x;
    if (i < n) p[i] = 0.f;
}

extern "C" void kernel_launch(void* const* d_in, const int* in_sizes, int n_in,
                              void* d_out, int out_size, void* d_ws, size_t ws_size,
                              hipStream_t stream)
{
    const float* x   = (const float*)d_in[0];
    const float* Wq  = (const float*)d_in[1];
    const float* bq  = (const float*)d_in[2];
    const float* Wk  = (const float*)d_in[3];
    const float* bk  = (const float*)d_in[4];
    const float* Wv  = (const float*)d_in[5];
    const float* bv  = (const float*)d_in[6];
    const float* Wfc = (const float*)d_in[7];
    const float* bfc = (const float*)d_in[8];
    float* out = (float*)d_out;
    float* ws = (float*)d_ws;

    float* q    = ws;                 // (B,C,N) fp32 post-rope/elu/scale
    float* k    = ws + SZ;            // (B,C,N) fp32; later attn PACKED output
    float* v    = ws + 2 * SZ;        // (B,C,N) fp32
    float* kv   = ws + 3 * SZ;        // (48,64,64)
    float* ksum = kv + 48 * 64 * 64;  // (48,64)
    float2* Ttab = (float2*)(ksum + 48 * 64);               // 96*64 float2 (48KB)
    unsigned short* Wp = (unsigned short*)(Ttab + 96 * 64); // 96*12288 ushorts
    unsigned* op = (unsigned*)k;      // packed attn output overwrites dead k

    const int nz = 48 * 64 * 64 + 48 * 64;
    zero_kernel<<<(nz + 255) / 256, 256, 0, stream>>>(kv, nz);
    trig_kernel<<<24, 256, 0, stream>>>(Ttab);
    pack_w_kernel<<<24, 256, 0, stream>>>(Wq, Wk, Wv, Wfc, Wp);
    mfma_gemm<0><<<dim3(32, 9, BATCH), 256, 0, stream>>>(x, Wp, Ttab, bq, bk, bv, q, k, v);
    kv_kernel<<<dim3(48, 16), 256, 0, stream>>>(k, v, kv, ksum);
    attn_kernel<<<dim3(32, 48), 256, 0, stream>>>(q, kv, ksum, op);
    mfma_gemm<1><<<dim3(32, 3, BATCH), 256, 0, stream>>>(op, Wp + (size_t)72 * 12288, Ttab,
                                                         bfc, bfc, bfc, out, out, out);
}

// Round 5
// 353.192 us; speedup vs baseline: 1.0249x; 1.0249x over previous
//
#include <hip/hip_runtime.h>
#include <math.h>

#define BATCH 8
#define CCH 384
#define NPIX 4096
#define NHEADS 6
#define SZ ((size_t)BATCH * CCH * NPIX) // elements per (B,C,N) buffer

typedef __attribute__((ext_vector_type(8))) short short8;  // 8 bf16 = 4 VGPR
typedef __attribute__((ext_vector_type(4))) float f32x4;   // MFMA acc

__device__ __forceinline__ float elu1(float x) { return x > 0.f ? x + 1.f : expf(x); }

__device__ __forceinline__ unsigned short bf16_rne(float f) {
    unsigned u = __builtin_bit_cast(unsigned, f);
    u += 0x7FFFu + ((u >> 16) & 1u);
    return (unsigned short)(u >> 16);
}
__device__ __forceinline__ float bf16_f(unsigned short h) {
    return __builtin_bit_cast(float, ((unsigned)h) << 16);
}
__device__ __forceinline__ unsigned packsplit(float v) {
    unsigned short hi = bf16_rne(v);
    unsigned short lo = bf16_rne(v - bf16_f(hi));
    return ((unsigned)hi << 16) | (unsigned)lo;
}

// ---------------------------------------------------------------------------
// Pack x (fp32) -> u32 (bf16_hi<<16 | bf16_lo), elementwise, vectorized.
// ---------------------------------------------------------------------------
__global__ __launch_bounds__(256) void pack_x_kernel(
    const float* __restrict__ X, unsigned* __restrict__ Xp)
{
    size_t i = ((size_t)blockIdx.x * 256 + threadIdx.x) * 4;
    float4 v = *(const float4*)(X + i);
    uint4 o;
    o.x = packsplit(v.x); o.y = packsplit(v.y);
    o.z = packsplit(v.z); o.w = packsplit(v.w);
    *(uint4*)(Xp + i) = o;
}

// ---------------------------------------------------------------------------
// Trig table: T[f][pos] = (sin, cos) of pos * 10000^(-f/96), f in 0..95, pos 0..63
// ---------------------------------------------------------------------------
__global__ __launch_bounds__(256) void trig_kernel(float2* __restrict__ T)
{
    const float KC = 0.13841367062030680f; // log2(10000)/96
    int idx = blockIdx.x * 256 + threadIdx.x; // 0..6143
    int f = idx >> 6, pos = idx & 63;
    float ang = (float)pos * exp2f(-KC * (float)f);
    float s, c;
    sincosf(ang, &s, &c);
    T[idx] = make_float2(s, c);
}

// ---------------------------------------------------------------------------
// Pack W (q,k,v,fc) into MFMA A-fragment order, split hi/lo bf16.
// f-blocks: 0..23 q (rope-permuted rows), 24..47 k, 48..71 v, 72..95 fc.
// Wp[f*12288 + c*1024 + hilo*512 + lane*8 + j] = W[ch(f,lane&15)][c*32+(lane>>4)*8+j]
// ---------------------------------------------------------------------------
__global__ __launch_bounds__(256) void pack_w_kernel(
    const float* __restrict__ Wq, const float* __restrict__ Wk,
    const float* __restrict__ Wv, const float* __restrict__ Wfc,
    unsigned short* __restrict__ Wp)
{
    const int tid = threadIdx.x;
    const int lane = tid & 63;
    const int f = blockIdx.x * 4 + (tid >> 6); // 0..95
    const int rloc = lane & 15;
    const int ks = (lane >> 4) * 8;

    const float* Wsel;
    int ch;
    if (f < 72) {
        int which = f / 24;
        int r = (f % 24) * 16 + rloc;
        if (which < 2) {
            int u = r >> 1;
            int cu = (u < 96) ? u : u + 96;
            ch = cu + 96 * (r & 1);
        } else {
            ch = r;
        }
        Wsel = (which == 0) ? Wq : (which == 1) ? Wk : Wv;
    } else {
        ch = (f - 72) * 16 + rloc;
        Wsel = Wfc;
    }

    for (int c = 0; c < 12; ++c) {
        short8 hv, lv;
#pragma unroll
        for (int j = 0; j < 8; ++j) {
            float v = Wsel[(size_t)ch * CCH + c * 32 + ks + j];
            unsigned short h = bf16_rne(v);
            hv[j] = (short)h;
            lv[j] = (short)bf16_rne(v - bf16_f(h));
        }
        size_t off = (size_t)f * 12288 + (size_t)c * 1024 + (size_t)lane * 8;
        *(short8*)(Wp + off) = hv;
        *(short8*)(Wp + off + 512) = lv;
    }
}

// ---------------------------------------------------------------------------
// Split-bf16 MFMA GEMM body, packed-u32 input, global_load_lds staging.
// LDS tile: linear u32 [32 k][128 col], written by global_load_lds (wave-
// uniform dest + lane*16B). Swizzle lives in the SOURCE address (16B granule
// XOR P(r)) and the READ address (granule XOR P(k)) -- rule 21 compliant.
// P(r) = (r&7) ^ (((r>>3)&1)<<2): read is 2 lanes/bank (free), write is
// contiguous 1KB per wave-call (conflict-free by construction).
// MODE 0: M=1152 (q,k,v stacked, q/k rows permuted), rope(table)+elu epilogue.
// MODE 1: M=384 (fc), bias epilogue, fp32 out.
// acc[i][jj][reg]: m = mt*64+i*16+(lane>>4)*4+reg, n = nblk*128+wn*64+jj*16+(lane&15)
// ---------------------------------------------------------------------------
template <int MODE>
__device__ __forceinline__ void gemm_body(
    const unsigned* __restrict__ Xin,
    const unsigned short* __restrict__ Wp,
    const float2* __restrict__ Ttab,
    const float* __restrict__ b0, const float* __restrict__ b1, const float* __restrict__ b2,
    float* __restrict__ O0, float* __restrict__ O1, float* __restrict__ O2)
{
    __shared__ unsigned Bs[32 * 128];

    const int tid = threadIdx.x;
    const int lane = tid & 63;
    const int wv = tid >> 6;
    const int wm = wv >> 1, wn = wv & 1;
    const int mt = blockIdx.y * 2 + wm;       // 64-row tile idx
    const int nblk = blockIdx.x;
    const int b = blockIdx.z;
    const int g = lane >> 4;                  // 0..3
    const int ln = lane & 15;

    f32x4 acc[4][4] = {};

    const unsigned short* wbase = Wp + (size_t)(mt * 4) * 12288 + (size_t)lane * 8;
    const unsigned* sbU = Xin + (size_t)b * CCH * NPIX + nblk * 128;

    // Per-lane staging source (constant across c): row within k-chunk and
    // inverse-swizzled granule.
    const int r_lo = (lane >> 5);             // 0/1 within a 2-row call

#pragma unroll 1
    for (int c = 0; c < 12; ++c) {
        __syncthreads();
#pragma unroll
        for (int t = 0; t < 4; ++t) {
            const int r = wv * 8 + t * 2 + r_lo;                     // k-row 0..31
            const int P = (r & 7) ^ (((r >> 3) & 1) << 2);
            const int cg = (lane & 31) ^ P;                          // source granule
            const unsigned* gsrc = sbU + (size_t)(c * 32 + r) * NPIX + 4 * cg;
            unsigned* ldst = &Bs[wv * 1024 + t * 256];               // wave-uniform
            __builtin_amdgcn_global_load_lds(
                (const __attribute__((address_space(1))) unsigned*)gsrc,
                (__attribute__((address_space(3))) unsigned*)ldst, 16, 0, 0);
        }
        __syncthreads();

        short8 ah[4], al[4];
#pragma unroll
        for (int i = 0; i < 4; ++i) {
            const unsigned short* p = wbase + (size_t)i * 12288 + c * 1024;
            ah[i] = *(const short8*)(p);
            al[i] = *(const short8*)(p + 512);
        }

#pragma unroll
        for (int jj = 0; jj < 4; ++jj) {
            const int colbase = wn * 64 + jj * 16 + ln;
            const int cg2 = colbase >> 2;
            const int cw = colbase & 3;
            short8 bh, bl;
#pragma unroll
            for (int j = 0; j < 8; ++j) {
                const int k = g * 8 + j;
                const int Pk = j ^ ((g & 1) << 2);   // (k&7)^(((k>>3)&1)<<2)
                unsigned uu = Bs[k * 128 + ((cg2 ^ Pk) << 2) + cw];
                bh[j] = (short)(uu >> 16);
                bl[j] = (short)(uu & 0xFFFFu);
            }
#pragma unroll
            for (int i = 0; i < 4; ++i) {
                acc[i][jj] = __builtin_amdgcn_mfma_f32_16x16x32_bf16(ah[i], bh, acc[i][jj], 0, 0, 0);
                acc[i][jj] = __builtin_amdgcn_mfma_f32_16x16x32_bf16(ah[i], bl, acc[i][jj], 0, 0, 0);
                acc[i][jj] = __builtin_amdgcn_mfma_f32_16x16x32_bf16(al[i], bh, acc[i][jj], 0, 0, 0);
            }
        }
    }

    const int ncol0 = nblk * 128 + wn * 64 + ln;

    if (MODE == 1) {
#pragma unroll
        for (int i = 0; i < 4; ++i) {
            const int rowb = mt * 64 + i * 16 + g * 4;
#pragma unroll
            for (int r = 0; r < 4; ++r) {
                const int row = rowb + r;
                const float bias = b0[row];
                float* orow = O0 + ((size_t)b * CCH + row) * NPIX;
#pragma unroll
                for (int jj = 0; jj < 4; ++jj)
                    orow[ncol0 + jj * 16] = acc[i][jj][r] + bias;
            }
        }
    } else {
        const int which = mt / 6;
        const int mloc = (mt % 6) * 64;
        const float* bsel = (which == 0) ? b0 : (which == 1) ? b1 : b2;
        float* osel = (which == 0) ? O0 : (which == 1) ? O1 : O2;
        if (which == 2) {
            // v: plain bias, fp32 out
#pragma unroll
            for (int i = 0; i < 4; ++i) {
                const int rowb = mloc + i * 16 + g * 4;
#pragma unroll
                for (int r = 0; r < 4; ++r) {
                    const int row = rowb + r;
                    const float bias = bsel[row];
                    float* orow = osel + ((size_t)b * CCH + row) * NPIX;
#pragma unroll
                    for (int jj = 0; jj < 4; ++jj)
                        orow[ncol0 + jj * 16] = acc[i][jj][r] + bias;
                }
            }
        } else {
            const float qs = (which == 0) ? 0.125f : 1.0f; // hd^-0.5 pre-elu for q
            const int posH = nblk * 2 + wn;                // n>>6, thread-constant
#pragma unroll
            for (int i = 0; i < 4; ++i) {
#pragma unroll
                for (int p = 0; p < 2; ++p) {
                    const int re = mloc + i * 16 + g * 4 + 2 * p; // even permuted row
                    const int u = re >> 1;
                    const bool isH = (u < 96);
                    const int cu = isH ? u : u + 96;
                    const int jA = isH ? (u >> 1) : ((u - 96) >> 1);
                    const float be = bsel[cu];
                    const float bo = bsel[cu + 96];
                    float* orE = osel + ((size_t)b * CCH + cu) * NPIX;
                    float* orO = orE + (size_t)96 * NPIX;
                    const float2* Ta = Ttab + jA * 64;
                    const float2* Tb = Ttab + (jA + 48) * 64;
                    if (isH) {
                        const float2 fa = Ta[posH];
                        const float2 fb = Tb[posH];
#pragma unroll
                        for (int jj = 0; jj < 4; ++jj) {
                            const int n = ncol0 + jj * 16;
                            const float te = acc[i][jj][2 * p] + be;
                            const float to = acc[i][jj][2 * p + 1] + bo;
                            orE[n] = elu1((te * fa.y - to * fa.x) * qs);
                            orO[n] = elu1((to * fb.y + te * fb.x) * qs);
                        }
                    } else {
#pragma unroll
                        for (int jj = 0; jj < 4; ++jj) {
                            const int n = ncol0 + jj * 16;
                            const int pw = jj * 16 + ln; // n & 63
                            const float2 fa = Ta[pw];
                            const float2 fb = Tb[pw];
                            const float te = acc[i][jj][2 * p] + be;
                            const float to = acc[i][jj][2 * p + 1] + bo;
                            orE[n] = elu1((te * fa.y - to * fa.x) * qs);
                            orO[n] = elu1((to * fb.y + te * fb.x) * qs);
                        }
                    }
                }
            }
        }
    }
}

__global__ __launch_bounds__(256, 2) void qkv_gemm(
    const unsigned* __restrict__ Xin, const unsigned short* __restrict__ Wp,
    const float2* __restrict__ Ttab,
    const float* __restrict__ b0, const float* __restrict__ b1, const float* __restrict__ b2,
    float* __restrict__ O0, float* __restrict__ O1, float* __restrict__ O2)
{
    gemm_body<0>(Xin, Wp, Ttab, b0, b1, b2, O0, O1, O2);
}

__global__ __launch_bounds__(256, 2) void fc_gemm(
    const unsigned* __restrict__ Xin, const unsigned short* __restrict__ Wp,
    const float2* __restrict__ Ttab,
    const float* __restrict__ b0,
    float* __restrict__ O0)
{
    gemm_body<1>(Xin, Wp, Ttab, b0, b0, b0, O0, O0, O0);
}

// ---------------------------------------------------------------------------
// kv[bh][d][e] = sum_n k[b,64h+d,n] * v[b,64h+e,n];  ksum[bh][d] = sum_n k
// ---------------------------------------------------------------------------
__global__ __launch_bounds__(256) void kv_kernel(
    const float* __restrict__ Kin, const float* __restrict__ Vin,
    float* __restrict__ KV, float* __restrict__ KS)
{
    __shared__ float Ks[32][68];
    __shared__ float Vs[32][68];
    const int tid = threadIdx.x;
    const int bh = blockIdx.x;
    const int ns = blockIdx.y;
    const int b = bh / NHEADS, h = bh % NHEADS;
    const float* kb = Kin + ((size_t)b * CCH + h * 64) * NPIX;
    const float* vb = Vin + ((size_t)b * CCH + h * 64) * NPIX;
    const int drow = tid >> 2;
    const int nl = (tid & 3) * 8;
    const int td = (tid & 15) * 4;
    const int te = (tid >> 4) * 4;

    float acc[4][4];
    float ks[4] = {0.f, 0.f, 0.f, 0.f};
#pragma unroll
    for (int i = 0; i < 4; ++i)
#pragma unroll
        for (int j = 0; j < 4; ++j) acc[i][j] = 0.f;

    for (int n0 = ns * 256; n0 < ns * 256 + 256; n0 += 32) {
        __syncthreads();
        const float* kr = kb + (size_t)drow * NPIX + n0 + nl;
        const float* vr = vb + (size_t)drow * NPIX + n0 + nl;
        float4 k0 = *(const float4*)kr;
        float4 k1 = *(const float4*)(kr + 4);
        float4 v0 = *(const float4*)vr;
        float4 v1 = *(const float4*)(vr + 4);
        Ks[nl + 0][drow] = k0.x; Ks[nl + 1][drow] = k0.y;
        Ks[nl + 2][drow] = k0.z; Ks[nl + 3][drow] = k0.w;
        Ks[nl + 4][drow] = k1.x; Ks[nl + 5][drow] = k1.y;
        Ks[nl + 6][drow] = k1.z; Ks[nl + 7][drow] = k1.w;
        Vs[nl + 0][drow] = v0.x; Vs[nl + 1][drow] = v0.y;
        Vs[nl + 2][drow] = v0.z; Vs[nl + 3][drow] = v0.w;
        Vs[nl + 4][drow] = v1.x; Vs[nl + 5][drow] = v1.y;
        Vs[nl + 6][drow] = v1.z; Vs[nl + 7][drow] = v1.w;
        __syncthreads();
#pragma unroll 8
        for (int nn = 0; nn < 32; ++nn) {
            float4 a = *(const float4*)&Ks[nn][td];
            float4 w = *(const float4*)&Vs[nn][te];
            float av[4] = {a.x, a.y, a.z, a.w};
            float wv2[4] = {w.x, w.y, w.z, w.w};
            ks[0] += av[0]; ks[1] += av[1]; ks[2] += av[2]; ks[3] += av[3];
#pragma unroll
            for (int i = 0; i < 4; ++i)
#pragma unroll
                for (int j = 0; j < 4; ++j) acc[i][j] += av[i] * wv2[j];
        }
    }

    float* kvb = KV + (size_t)bh * 64 * 64;
#pragma unroll
    for (int i = 0; i < 4; ++i)
#pragma unroll
        for (int j = 0; j < 4; ++j)
            atomicAdd(&kvb[(td + i) * 64 + (te + j)], acc[i][j]);
    if (te == 0) {
#pragma unroll
        for (int i = 0; i < 4; ++i) atomicAdd(&KS[bh * 64 + td + i], ks[i]);
    }
}

// ---------------------------------------------------------------------------
// out[b,64h+e,n] = (sum_d q*kv) / (sum_d q*ksum + 1e-6), written PACKED u32.
// ---------------------------------------------------------------------------
__global__ __launch_bounds__(256) void attn_kernel(
    const float* __restrict__ Q, const float* __restrict__ KV,
    const float* __restrict__ KS, unsigned* __restrict__ O)
{
    __shared__ float Qs[64][132];
    __shared__ float KVs[64][64];
    __shared__ float KSs[64];
    const int tid = threadIdx.x;
    const int n0 = blockIdx.x * 128;
    const int bh = blockIdx.y;
    const int b = bh / NHEADS, h = bh % NHEADS;
    const float* qb = Q + ((size_t)b * CCH + h * 64) * NPIX;

    {
        const int row = tid >> 2;
        const int c0 = (tid & 3) * 32;
        const float* qr = qb + (size_t)row * NPIX + n0 + c0;
#pragma unroll
        for (int j = 0; j < 8; ++j)
            *(float4*)&Qs[row][c0 + j * 4] = *(const float4*)&qr[j * 4];
        const int kc = (tid & 3) * 16;
        const float* kvr = KV + (size_t)bh * 4096 + (size_t)row * 64 + kc;
#pragma unroll
        for (int j = 0; j < 4; ++j)
            *(float4*)&KVs[row][kc + j * 4] = *(const float4*)&kvr[j * 4];
        if (tid < 64) KSs[tid] = KS[bh * 64 + tid];
    }
    __syncthreads();

    const int tx = tid & 31;
    const int ty = tid >> 5;
    float acc[8][4];
    float accn[4] = {0.f, 0.f, 0.f, 0.f};
#pragma unroll
    for (int r = 0; r < 8; ++r)
#pragma unroll
        for (int j = 0; j < 4; ++j) acc[r][j] = 0.f;

#pragma unroll 8
    for (int d = 0; d < 64; ++d) {
        float4 qv = *(const float4*)&Qs[d][tx * 4];
        float qa[4] = {qv.x, qv.y, qv.z, qv.w};
        float ksv = KSs[d];
#pragma unroll
        for (int j = 0; j < 4; ++j) accn[j] += ksv * qa[j];
        float4 k0 = *(const float4*)&KVs[d][ty * 8];
        float4 k1 = *(const float4*)&KVs[d][ty * 8 + 4];
        float kva[8] = {k0.x, k0.y, k0.z, k0.w, k1.x, k1.y, k1.z, k1.w};
#pragma unroll
        for (int r = 0; r < 8; ++r)
#pragma unroll
            for (int j = 0; j < 4; ++j) acc[r][j] += kva[r] * qa[j];
    }

    float rcp[4];
#pragma unroll
    for (int j = 0; j < 4; ++j) rcp[j] = 1.f / (accn[j] + 1e-6f);
#pragma unroll
    for (int r = 0; r < 8; ++r) {
        unsigned* orow = O + ((size_t)b * CCH + h * 64 + ty * 8 + r) * NPIX + n0 + tx * 4;
        uint4 o4;
        o4.x = packsplit(acc[r][0] * rcp[0]);
        o4.y = packsplit(acc[r][1] * rcp[1]);
        o4.z = packsplit(acc[r][2] * rcp[2]);
        o4.w = packsplit(acc[r][3] * rcp[3]);
        *(uint4*)orow = o4;
    }
}

__global__ void zero_kernel(float* p, int n)
{
    int i = blockIdx.x * blockDim.x + threadIdx.x;
    if (i < n) p[i] = 0.f;
}

extern "C" void kernel_launch(void* const* d_in, const int* in_sizes, int n_in,
                              void* d_out, int out_size, void* d_ws, size_t ws_size,
                              hipStream_t stream)
{
    const float* x   = (const float*)d_in[0];
    const float* Wq  = (const float*)d_in[1];
    const float* bq  = (const float*)d_in[2];
    const float* Wk  = (const float*)d_in[3];
    const float* bk  = (const float*)d_in[4];
    const float* Wv  = (const float*)d_in[5];
    const float* bv  = (const float*)d_in[6];
    const float* Wfc = (const float*)d_in[7];
    const float* bfc = (const float*)d_in[8];
    float* out = (float*)d_out;
    float* ws = (float*)d_ws;

    float* q    = ws;                 // (B,C,N) fp32 post-rope/elu/scale
    float* k    = ws + SZ;            // (B,C,N) fp32; later attn PACKED output
    float* v    = ws + 2 * SZ;        // (B,C,N) fp32
    float* kv   = ws + 3 * SZ;        // (48,64,64)
    float* ksum = kv + 48 * 64 * 64;  // (48,64)
    float2* Ttab = (float2*)(ksum + 48 * 64);               // 96*64 float2 (48KB)
    unsigned short* Wp = (unsigned short*)(Ttab + 96 * 64); // 96*12288 ushorts
    unsigned* xp = (unsigned*)d_out;  // packed x aliases d_out (dead until FC)
    unsigned* op = (unsigned*)k;      // packed attn output overwrites dead k

    const int nz = 48 * 64 * 64 + 48 * 64;
    zero_kernel<<<(nz + 255) / 256, 256, 0, stream>>>(kv, nz);
    trig_kernel<<<24, 256, 0, stream>>>(Ttab);
    pack_w_kernel<<<24, 256, 0, stream>>>(Wq, Wk, Wv, Wfc, Wp);
    pack_x_kernel<<<(int)(SZ / 1024), 256, 0, stream>>>(x, xp);
    qkv_gemm<<<dim3(32, 9, BATCH), 256, 0, stream>>>(xp, Wp, Ttab, bq, bk, bv, q, k, v);
    kv_kernel<<<dim3(48, 16), 256, 0, stream>>>(k, v, kv, ksum);
    attn_kernel<<<dim3(32, 48), 256, 0, stream>>>(q, kv, ksum, op);
    fc_gemm<<<dim3(32, 3, BATCH), 256, 0, stream>>>(op, Wp + (size_t)72 * 12288, Ttab,
                                                    bfc, out);
}